// Round 2
// baseline (235.350 us; speedup 1.0000x reference)
//
#include <hip/hip_runtime.h>
#include <math.h>

#define B_    32
#define C_    128
#define HW_   16384          // 128*128
#define NPIX  524288         // B_*HW_
#define EPSF  1e-5f

__device__ __forceinline__ float wave_sum(float v) {
#pragma unroll
    for (int off = 32; off > 0; off >>= 1) v += __shfl_down(v, off, 64);
    return v;
}

// Kernel 1: per-pixel channel mean/max over C=128, emit feat[B][2][HW],
// accumulate BN1 stats (sum, sumsq per feat-channel) via block reduce + atomics.
__global__ __launch_bounds__(256) void k_reduce(const float* __restrict__ x,
                                                float* __restrict__ feat,
                                                float* __restrict__ stats) {
    int t  = blockIdx.x * 256 + threadIdx.x;   // 131072 threads, 4 pixels each
    int b  = t >> 12;                          // / 4096
    int hw = (t & 4095) << 2;                  // float4 pixel group
    const float4* xp = reinterpret_cast<const float4*>(x + (size_t)b * C_ * HW_ + hw);
    float4 s = make_float4(0.f, 0.f, 0.f, 0.f);
    float4 m = make_float4(-INFINITY, -INFINITY, -INFINITY, -INFINITY);
#pragma unroll 8
    for (int c = 0; c < C_; ++c) {
        float4 v = xp[(size_t)c * (HW_ / 4)];
        s.x += v.x; s.y += v.y; s.z += v.z; s.w += v.w;
        m.x = fmaxf(m.x, v.x); m.y = fmaxf(m.y, v.y);
        m.z = fmaxf(m.z, v.z); m.w = fmaxf(m.w, v.w);
    }
    const float inv = 1.0f / 128.0f;
    float4 a = make_float4(s.x * inv, s.y * inv, s.z * inv, s.w * inv);
    float* fb = feat + (size_t)b * 2 * HW_ + hw;
    *reinterpret_cast<float4*>(fb)       = a;   // channel 0 = avg
    *reinterpret_cast<float4*>(fb + HW_) = m;   // channel 1 = max

    float vals[4];
    vals[0] = a.x + a.y + a.z + a.w;
    vals[1] = a.x*a.x + a.y*a.y + a.z*a.z + a.w*a.w;
    vals[2] = m.x + m.y + m.z + m.w;
    vals[3] = m.x*m.x + m.y*m.y + m.z*m.z + m.w*m.w;

    __shared__ float red[4];
    int lane = threadIdx.x & 63, wid = threadIdx.x >> 6;
#pragma unroll
    for (int i = 0; i < 4; ++i) {
        float v = wave_sum(vals[i]);
        if (lane == 0) red[wid] = v;
        __syncthreads();
        if (threadIdx.x == 0) atomicAdd(stats + i, red[0] + red[1] + red[2] + red[3]);
        __syncthreads();
    }
}

// Kernel 2: BN1 (params derived from stats in-kernel, fused into operand load;
// OOB padding contributes 0 post-BN, matching reference) + 7x7x2 conv,
// accumulate BN2 stats.
__global__ __launch_bounds__(256) void k_conv(const float* __restrict__ feat,
                                              const float* __restrict__ cw,
                                              const float* __restrict__ g1,
                                              const float* __restrict__ be1,
                                              float* __restrict__ convout,
                                              float* __restrict__ stats) {
    __shared__ float w_s[98];
    __shared__ float sc_s[2], sh_s[2];
    if (threadIdx.x < 98) w_s[threadIdx.x] = cw[threadIdx.x];
    if (threadIdx.x < 2) {
        const float invn = 1.0f / (float)NPIX;
        int c = threadIdx.x;
        float mean = stats[2 * c] * invn;
        float var  = stats[2 * c + 1] * invn - mean * mean;
        float s    = g1[c] / sqrtf(var + EPSF);
        sc_s[c] = s;
        sh_s[c] = be1[c] - mean * s;
    }
    __syncthreads();

    int t  = blockIdx.x * 256 + threadIdx.x;   // 524288 threads, 1 pixel each
    int b  = t >> 14;
    int hw = t & 16383;
    int h  = hw >> 7, w = hw & 127;
    const float* fb = feat + (size_t)b * 2 * HW_;
    float acc = 0.f;
#pragma unroll
    for (int c = 0; c < 2; ++c) {
        float sc = sc_s[c], sh = sh_s[c];
#pragma unroll
        for (int kh = 0; kh < 7; ++kh) {
            int hh = h + kh - 3;
            if ((unsigned)hh >= 128u) continue;
#pragma unroll
            for (int kw = 0; kw < 7; ++kw) {
                int ww = w + kw - 3;
                if ((unsigned)ww >= 128u) continue;
                acc += (fb[c * HW_ + hh * 128 + ww] * sc + sh) * w_s[c * 49 + kh * 7 + kw];
            }
        }
    }
    convout[t] = acc;

    __shared__ float red[4];
    int lane = threadIdx.x & 63, wid = threadIdx.x >> 6;
    float v = wave_sum(acc);
    if (lane == 0) red[wid] = v;
    __syncthreads();
    if (threadIdx.x == 0) atomicAdd(stats + 4, red[0] + red[1] + red[2] + red[3]);
    __syncthreads();
    v = wave_sum(acc * acc);
    if (lane == 0) red[wid] = v;
    __syncthreads();
    if (threadIdx.x == 0) atomicAdd(stats + 5, red[0] + red[1] + red[2] + red[3]);
}

// Kernel 3: att = sigmoid(BN2(conv)) recomputed per thread (conv buf is 2 MB,
// L2/L3-resident); out = att * x. Streams 256 MB read + 256 MB write.
__global__ __launch_bounds__(256) void k_apply(const float* __restrict__ x,
                                               const float* __restrict__ convout,
                                               const float* __restrict__ g2,
                                               const float* __restrict__ be2,
                                               const float* __restrict__ stats,
                                               float* __restrict__ out) {
    int t  = blockIdx.x * 256 + threadIdx.x;   // 16777216 threads, float4 each
    int hw = (t & 4095) << 2;
    int c  = (t >> 12) & 127;
    int b  = t >> 19;

    const float invn = 1.0f / (float)NPIX;
    float mean = stats[4] * invn;
    float var  = stats[5] * invn - mean * mean;
    float s    = g2[0] / sqrtf(var + EPSF);
    float sh   = be2[0] - mean * s;

    float4 cv = *reinterpret_cast<const float4*>(convout + b * HW_ + hw);
    float4 att;
    att.x = 1.f / (1.f + expf(-(cv.x * s + sh)));
    att.y = 1.f / (1.f + expf(-(cv.y * s + sh)));
    att.z = 1.f / (1.f + expf(-(cv.z * s + sh)));
    att.w = 1.f / (1.f + expf(-(cv.w * s + sh)));

    size_t xi = ((size_t)(b * 128 + c)) * HW_ + hw;
    float4 xv = *reinterpret_cast<const float4*>(x + xi);
    float4 o  = make_float4(xv.x * att.x, xv.y * att.y, xv.z * att.z, xv.w * att.w);
    *reinterpret_cast<float4*>(out + xi) = o;
}

extern "C" void kernel_launch(void* const* d_in, const int* in_sizes, int n_in,
                              void* d_out, int out_size, void* d_ws, size_t ws_size,
                              hipStream_t stream) {
    const float* x  = (const float*)d_in[0];
    const float* cw = (const float*)d_in[1];
    const float* g1 = (const float*)d_in[2];
    const float* b1 = (const float*)d_in[3];
    const float* g2 = (const float*)d_in[4];
    const float* b2 = (const float*)d_in[5];
    float* out = (float*)d_out;

    char* ws = (char*)d_ws;
    float* feat    = (float*)ws;                          // 4 MiB: [B][2][HW]
    float* convout = (float*)(ws + 4u * 1024 * 1024);     // 2 MiB: [B][HW]
    float* stats   = (float*)(ws + 6u * 1024 * 1024);     // 8 floats

    hipMemsetAsync(stats, 0, 8 * sizeof(float), stream);  // ws is NOT re-poisoned; must zero every call
    k_reduce<<<512,   256, 0, stream>>>(x, feat, stats);
    k_conv  <<<2048,  256, 0, stream>>>(feat, cw, g1, b1, convout, stats);
    // B*C*HW/4 float4-threads = 16,777,216 -> 65536 blocks (round-1 bug: was 16384)
    k_apply <<<65536, 256, 0, stream>>>(x, convout, g2, b2, stats, out);
}

// Round 4
// 201.422 us; speedup vs baseline: 1.1684x; 1.1684x over previous
//
#include <hip/hip_runtime.h>
#include <math.h>

#define B_    32
#define C_    128
#define HW_   16384          // 128*128
#define NPIX  524288         // B_*HW_
#define EPSF  1e-5f

typedef float vfloat4 __attribute__((ext_vector_type(4)));  // native vec for nontemporal builtin

__device__ __forceinline__ float wave_sum(float v) {
#pragma unroll
    for (int off = 32; off > 0; off >>= 1) v += __shfl_down(v, off, 64);
    return v;
}

// Kernel 1: per-pixel channel mean/max over C=128 with the channel loop split
// across wave halves (lanes 0-31: ch 0-63, lanes 32-63: ch 64-127; combine via
// shfl_xor 32). Emits feat[B][2][HW], accumulates BN1 stats via atomics.
__global__ __launch_bounds__(256) void k_reduce(const float* __restrict__ x,
                                                float* __restrict__ feat,
                                                float* __restrict__ stats) {
    int lane = threadIdx.x & 63, wid = threadIdx.x >> 6;
    int pg   = (blockIdx.x * 4 + wid) * 32 + (lane & 31);  // float4-pixel group, 131072 total
    int b    = pg >> 12;
    int hw   = (pg & 4095) << 2;
    int ch0  = (lane >> 5) * 64;                           // 0 or 64

    const float4* xp = reinterpret_cast<const float4*>(
        x + (size_t)b * C_ * HW_ + (size_t)ch0 * HW_ + hw);
    float4 s = make_float4(0.f, 0.f, 0.f, 0.f);
    float4 m = make_float4(-INFINITY, -INFINITY, -INFINITY, -INFINITY);
#pragma unroll 8
    for (int c = 0; c < 64; ++c) {
        float4 v = xp[(size_t)c * (HW_ / 4)];
        s.x += v.x; s.y += v.y; s.z += v.z; s.w += v.w;
        m.x = fmaxf(m.x, v.x); m.y = fmaxf(m.y, v.y);
        m.z = fmaxf(m.z, v.z); m.w = fmaxf(m.w, v.w);
    }
    // combine halves (both halves end with identical full-channel results)
    s.x += __shfl_xor(s.x, 32, 64); s.y += __shfl_xor(s.y, 32, 64);
    s.z += __shfl_xor(s.z, 32, 64); s.w += __shfl_xor(s.w, 32, 64);
    m.x = fmaxf(m.x, __shfl_xor(m.x, 32, 64)); m.y = fmaxf(m.y, __shfl_xor(m.y, 32, 64));
    m.z = fmaxf(m.z, __shfl_xor(m.z, 32, 64)); m.w = fmaxf(m.w, __shfl_xor(m.w, 32, 64));

    const float inv = 1.0f / 128.0f;
    float4 a = make_float4(s.x * inv, s.y * inv, s.z * inv, s.w * inv);
    float* fb = feat + (size_t)b * 2 * HW_ + hw;
    if (lane < 32) *reinterpret_cast<float4*>(fb)       = a;   // avg plane
    else           *reinterpret_cast<float4*>(fb + HW_) = m;   // max plane

    // stats (each value duplicated in both halves -> scale block total by 0.5)
    float vals[4];
    vals[0] = a.x + a.y + a.z + a.w;
    vals[1] = a.x*a.x + a.y*a.y + a.z*a.z + a.w*a.w;
    vals[2] = m.x + m.y + m.z + m.w;
    vals[3] = m.x*m.x + m.y*m.y + m.z*m.z + m.w*m.w;

    __shared__ float red[4];
#pragma unroll
    for (int i = 0; i < 4; ++i) {
        float v = wave_sum(vals[i]);
        if (lane == 0) red[wid] = v;
        __syncthreads();
        if (threadIdx.x == 0)
            atomicAdd(stats + i, 0.5f * (red[0] + red[1] + red[2] + red[3]));
        __syncthreads();
    }
}

// Kernel 2: BN1 affine fused into operand load (OOB contributes 0 post-BN,
// matching pad-after-BN) + 7x7x2 conv, 4 output pixels per thread with
// row-reuse (10-float row serves 4 overlapping 7-tap windows). BN2 stats.
__global__ __launch_bounds__(256) void k_conv(const float* __restrict__ feat,
                                              const float* __restrict__ cw,
                                              const float* __restrict__ g1,
                                              const float* __restrict__ be1,
                                              float* __restrict__ convout,
                                              float* __restrict__ stats) {
    __shared__ float w_s[98];
    __shared__ float sc_s[2], sh_s[2];
    if (threadIdx.x < 98) w_s[threadIdx.x] = cw[threadIdx.x];
    if (threadIdx.x < 2) {
        const float invn = 1.0f / (float)NPIX;
        int c = threadIdx.x;
        float mean = stats[2 * c] * invn;
        float var  = stats[2 * c + 1] * invn - mean * mean;
        float sc   = g1[c] / sqrtf(var + EPSF);
        sc_s[c] = sc;
        sh_s[c] = be1[c] - mean * sc;
    }
    __syncthreads();

    int t  = blockIdx.x * 256 + threadIdx.x;   // 131072 threads, 4 pixels each
    int b  = t >> 12;
    int pg = t & 4095;
    int h  = pg >> 5;
    int w4 = (pg & 31) << 2;                   // output col base (0,4,...,124)
    const float* fb = feat + (size_t)b * 2 * HW_;

    float acc0 = 0.f, acc1 = 0.f, acc2 = 0.f, acc3 = 0.f;
#pragma unroll
    for (int c = 0; c < 2; ++c) {
        float sc = sc_s[c], sh = sh_s[c];
        const float* fc = fb + c * HW_;
#pragma unroll
        for (int kh = 0; kh < 7; ++kh) {
            int hh = h + kh - 3;
            if ((unsigned)hh >= 128u) continue;
            const float* row = fc + hh * 128;
            float v[10];
#pragma unroll
            for (int i = 0; i < 10; ++i) {
                int ww = w4 - 3 + i;
                v[i] = ((unsigned)ww < 128u) ? row[ww] * sc + sh : 0.f;
            }
#pragma unroll
            for (int kw = 0; kw < 7; ++kw) {
                float wt = w_s[c * 49 + kh * 7 + kw];
                acc0 += v[kw]     * wt;
                acc1 += v[kw + 1] * wt;
                acc2 += v[kw + 2] * wt;
                acc3 += v[kw + 3] * wt;
            }
        }
    }
    *reinterpret_cast<float4*>(convout + (size_t)b * HW_ + h * 128 + w4) =
        make_float4(acc0, acc1, acc2, acc3);

    __shared__ float red[4];
    int lane = threadIdx.x & 63, wid = threadIdx.x >> 6;
    float v = wave_sum(acc0 + acc1 + acc2 + acc3);
    if (lane == 0) red[wid] = v;
    __syncthreads();
    if (threadIdx.x == 0) atomicAdd(stats + 4, red[0] + red[1] + red[2] + red[3]);
    __syncthreads();
    v = wave_sum(acc0*acc0 + acc1*acc1 + acc2*acc2 + acc3*acc3);
    if (lane == 0) red[wid] = v;
    __syncthreads();
    if (threadIdx.x == 0) atomicAdd(stats + 5, red[0] + red[1] + red[2] + red[3]);
}

// Kernel 3: att = sigmoid(BN2(conv)); out = att * x.
// x read should largely hit the 256 MiB Infinity Cache (populated by k_reduce,
// same traversal order). out uses NONTEMPORAL stores so the 268 MB of output
// does not evict x from L3 (also keeps x resident across graph replays).
__global__ __launch_bounds__(256) void k_apply(const float* __restrict__ x,
                                               const float* __restrict__ convout,
                                               const float* __restrict__ g2,
                                               const float* __restrict__ be2,
                                               const float* __restrict__ stats,
                                               float* __restrict__ out) {
    int t  = blockIdx.x * 256 + threadIdx.x;   // 16,777,216 threads, float4 each
    int hw = (t & 4095) << 2;
    int c  = (t >> 12) & 127;
    int b  = t >> 19;

    const float invn = 1.0f / (float)NPIX;
    float mean = stats[4] * invn;
    float var  = stats[5] * invn - mean * mean;
    float s    = g2[0] / sqrtf(var + EPSF);
    float sh   = be2[0] - mean * s;

    float4 cv = *reinterpret_cast<const float4*>(convout + b * HW_ + hw);
    float4 att;
    att.x = 1.f / (1.f + __expf(-(cv.x * s + sh)));
    att.y = 1.f / (1.f + __expf(-(cv.y * s + sh)));
    att.z = 1.f / (1.f + __expf(-(cv.z * s + sh)));
    att.w = 1.f / (1.f + __expf(-(cv.w * s + sh)));

    size_t xi = ((size_t)(b * 128 + c)) * HW_ + hw;
    float4 xv = *reinterpret_cast<const float4*>(x + xi);
    vfloat4 o = { xv.x * att.x, xv.y * att.y, xv.z * att.z, xv.w * att.w };
    __builtin_nontemporal_store(o, reinterpret_cast<vfloat4*>(out + xi));
}

extern "C" void kernel_launch(void* const* d_in, const int* in_sizes, int n_in,
                              void* d_out, int out_size, void* d_ws, size_t ws_size,
                              hipStream_t stream) {
    const float* x  = (const float*)d_in[0];
    const float* cw = (const float*)d_in[1];
    const float* g1 = (const float*)d_in[2];
    const float* b1 = (const float*)d_in[3];
    const float* g2 = (const float*)d_in[4];
    const float* b2 = (const float*)d_in[5];
    float* out = (float*)d_out;

    char* ws = (char*)d_ws;
    float* feat    = (float*)ws;                          // 4 MiB: [B][2][HW]
    float* convout = (float*)(ws + 4u * 1024 * 1024);     // 2 MiB: [B][HW]
    float* stats   = (float*)(ws + 6u * 1024 * 1024);     // 8 floats

    (void)hipMemsetAsync(stats, 0, 8 * sizeof(float), stream);  // ws is NOT re-poisoned; must zero every call
    k_reduce<<<1024,  256, 0, stream>>>(x, feat, stats);
    k_conv  <<<512,   256, 0, stream>>>(feat, cw, g1, b1, convout, stats);
    k_apply <<<65536, 256, 0, stream>>>(x, convout, g2, b2, stats, out);
}

// Round 5
// 194.498 us; speedup vs baseline: 1.2100x; 1.0356x over previous
//
#include <hip/hip_runtime.h>
#include <math.h>

#define B_    32
#define C_    128
#define HW_   16384          // 128*128
#define NPIX  524288         // B_*HW_
#define EPSF  1e-5f

typedef float vfloat4 __attribute__((ext_vector_type(4)));  // native vec for nontemporal builtin

__device__ __forceinline__ float wave_sum(float v) {
#pragma unroll
    for (int off = 32; off > 0; off >>= 1) v += __shfl_down(v, off, 64);
    return v;
}

// Kernel 1: per-pixel channel mean/max over C=128 with the channel loop split
// across wave halves (lanes 0-31: ch 0-63, lanes 32-63: ch 64-127; combine via
// shfl_xor 32). Emits feat[B][2][HW], accumulates BN1 stats via atomics.
// Reads x FORWARD -> at completion the TAIL of x is L3-hot (k_apply exploits).
__global__ __launch_bounds__(256) void k_reduce(const float* __restrict__ x,
                                                float* __restrict__ feat,
                                                float* __restrict__ stats) {
    int lane = threadIdx.x & 63, wid = threadIdx.x >> 6;
    int pg   = (blockIdx.x * 4 + wid) * 32 + (lane & 31);  // float4-pixel group, 131072 total
    int b    = pg >> 12;
    int hw   = (pg & 4095) << 2;
    int ch0  = (lane >> 5) * 64;                           // 0 or 64

    const float4* xp = reinterpret_cast<const float4*>(
        x + (size_t)b * C_ * HW_ + (size_t)ch0 * HW_ + hw);
    float4 s = make_float4(0.f, 0.f, 0.f, 0.f);
    float4 m = make_float4(-INFINITY, -INFINITY, -INFINITY, -INFINITY);
#pragma unroll 8
    for (int c = 0; c < 64; ++c) {
        float4 v = xp[(size_t)c * (HW_ / 4)];
        s.x += v.x; s.y += v.y; s.z += v.z; s.w += v.w;
        m.x = fmaxf(m.x, v.x); m.y = fmaxf(m.y, v.y);
        m.z = fmaxf(m.z, v.z); m.w = fmaxf(m.w, v.w);
    }
    // combine halves (both halves end with identical full-channel results)
    s.x += __shfl_xor(s.x, 32, 64); s.y += __shfl_xor(s.y, 32, 64);
    s.z += __shfl_xor(s.z, 32, 64); s.w += __shfl_xor(s.w, 32, 64);
    m.x = fmaxf(m.x, __shfl_xor(m.x, 32, 64)); m.y = fmaxf(m.y, __shfl_xor(m.y, 32, 64));
    m.z = fmaxf(m.z, __shfl_xor(m.z, 32, 64)); m.w = fmaxf(m.w, __shfl_xor(m.w, 32, 64));

    const float inv = 1.0f / 128.0f;
    float4 a = make_float4(s.x * inv, s.y * inv, s.z * inv, s.w * inv);
    float* fb = feat + (size_t)b * 2 * HW_ + hw;
    if (lane < 32) *reinterpret_cast<float4*>(fb)       = a;   // avg plane
    else           *reinterpret_cast<float4*>(fb + HW_) = m;   // max plane

    // stats (each value duplicated in both halves -> scale block total by 0.5)
    float vals[4];
    vals[0] = a.x + a.y + a.z + a.w;
    vals[1] = a.x*a.x + a.y*a.y + a.z*a.z + a.w*a.w;
    vals[2] = m.x + m.y + m.z + m.w;
    vals[3] = m.x*m.x + m.y*m.y + m.z*m.z + m.w*m.w;

    __shared__ float red[4];
#pragma unroll
    for (int i = 0; i < 4; ++i) {
        float v = wave_sum(vals[i]);
        if (lane == 0) red[wid] = v;
        __syncthreads();
        if (threadIdx.x == 0)
            atomicAdd(stats + i, 0.5f * (red[0] + red[1] + red[2] + red[3]));
        __syncthreads();
    }
}

// Kernel 2: BN1 affine fused into operand load (OOB contributes 0 post-BN,
// matching pad-after-BN) + 7x7x2 conv, 4 output pixels per thread with
// row-reuse (10-float row serves 4 overlapping 7-tap windows). BN2 stats.
__global__ __launch_bounds__(256) void k_conv(const float* __restrict__ feat,
                                              const float* __restrict__ cw,
                                              const float* __restrict__ g1,
                                              const float* __restrict__ be1,
                                              float* __restrict__ convout,
                                              float* __restrict__ stats) {
    __shared__ float w_s[98];
    __shared__ float sc_s[2], sh_s[2];
    if (threadIdx.x < 98) w_s[threadIdx.x] = cw[threadIdx.x];
    if (threadIdx.x < 2) {
        const float invn = 1.0f / (float)NPIX;
        int c = threadIdx.x;
        float mean = stats[2 * c] * invn;
        float var  = stats[2 * c + 1] * invn - mean * mean;
        float sc   = g1[c] / sqrtf(var + EPSF);
        sc_s[c] = sc;
        sh_s[c] = be1[c] - mean * sc;
    }
    __syncthreads();

    int t  = blockIdx.x * 256 + threadIdx.x;   // 131072 threads, 4 pixels each
    int b  = t >> 12;
    int pg = t & 4095;
    int h  = pg >> 5;
    int w4 = (pg & 31) << 2;                   // output col base (0,4,...,124)
    const float* fb = feat + (size_t)b * 2 * HW_;

    float acc0 = 0.f, acc1 = 0.f, acc2 = 0.f, acc3 = 0.f;
#pragma unroll
    for (int c = 0; c < 2; ++c) {
        float sc = sc_s[c], sh = sh_s[c];
        const float* fc = fb + c * HW_;
#pragma unroll
        for (int kh = 0; kh < 7; ++kh) {
            int hh = h + kh - 3;
            if ((unsigned)hh >= 128u) continue;
            const float* row = fc + hh * 128;
            float v[10];
#pragma unroll
            for (int i = 0; i < 10; ++i) {
                int ww = w4 - 3 + i;
                v[i] = ((unsigned)ww < 128u) ? row[ww] * sc + sh : 0.f;
            }
#pragma unroll
            for (int kw = 0; kw < 7; ++kw) {
                float wt = w_s[c * 49 + kh * 7 + kw];
                acc0 += v[kw]     * wt;
                acc1 += v[kw + 1] * wt;
                acc2 += v[kw + 2] * wt;
                acc3 += v[kw + 3] * wt;
            }
        }
    }
    *reinterpret_cast<float4*>(convout + (size_t)b * HW_ + h * 128 + w4) =
        make_float4(acc0, acc1, acc2, acc3);

    __shared__ float red[4];
    int lane = threadIdx.x & 63, wid = threadIdx.x >> 6;
    float v = wave_sum(acc0 + acc1 + acc2 + acc3);
    if (lane == 0) red[wid] = v;
    __syncthreads();
    if (threadIdx.x == 0) atomicAdd(stats + 4, red[0] + red[1] + red[2] + red[3]);
    __syncthreads();
    v = wave_sum(acc0*acc0 + acc1*acc1 + acc2*acc2 + acc3*acc3);
    if (lane == 0) red[wid] = v;
    __syncthreads();
    if (threadIdx.x == 0) atomicAdd(stats + 5, red[0] + red[1] + red[2] + red[3]);
}

// Kernel 3: att = sigmoid(BN2(conv)); out = att * x.
// REVERSED block order: x is 268.4 MB vs 256 MiB L3 -- a forward re-read after
// k_reduce's forward pass gets ~0% hits (sequential LRU pathology); reading
// back-to-front consumes the freshest lines first. out stores stay
// nontemporal so the write stream doesn't evict x.
__global__ __launch_bounds__(256) void k_apply(const float* __restrict__ x,
                                               const float* __restrict__ convout,
                                               const float* __restrict__ g2,
                                               const float* __restrict__ be2,
                                               const float* __restrict__ stats,
                                               float* __restrict__ out) {
    int t  = (gridDim.x - 1 - blockIdx.x) * 256 + threadIdx.x;  // reverse traversal
    int hw = (t & 4095) << 2;
    int c  = (t >> 12) & 127;
    int b  = t >> 19;

    const float invn = 1.0f / (float)NPIX;
    float mean = stats[4] * invn;
    float var  = stats[5] * invn - mean * mean;
    float s    = g2[0] / sqrtf(var + EPSF);
    float sh   = be2[0] - mean * s;

    float4 cv = *reinterpret_cast<const float4*>(convout + b * HW_ + hw);
    float4 att;
    att.x = 1.f / (1.f + __expf(-(cv.x * s + sh)));
    att.y = 1.f / (1.f + __expf(-(cv.y * s + sh)));
    att.z = 1.f / (1.f + __expf(-(cv.z * s + sh)));
    att.w = 1.f / (1.f + __expf(-(cv.w * s + sh)));

    size_t xi = ((size_t)(b * 128 + c)) * HW_ + hw;
    float4 xv = *reinterpret_cast<const float4*>(x + xi);
    vfloat4 o = { xv.x * att.x, xv.y * att.y, xv.z * att.z, xv.w * att.w };
    __builtin_nontemporal_store(o, reinterpret_cast<vfloat4*>(out + xi));
}

extern "C" void kernel_launch(void* const* d_in, const int* in_sizes, int n_in,
                              void* d_out, int out_size, void* d_ws, size_t ws_size,
                              hipStream_t stream) {
    const float* x  = (const float*)d_in[0];
    const float* cw = (const float*)d_in[1];
    const float* g1 = (const float*)d_in[2];
    const float* b1 = (const float*)d_in[3];
    const float* g2 = (const float*)d_in[4];
    const float* b2 = (const float*)d_in[5];
    float* out = (float*)d_out;

    char* ws = (char*)d_ws;
    float* feat    = (float*)ws;                          // 4 MiB: [B][2][HW]
    float* convout = (float*)(ws + 4u * 1024 * 1024);     // 2 MiB: [B][HW]
    float* stats   = (float*)(ws + 6u * 1024 * 1024);     // 8 floats

    (void)hipMemsetAsync(stats, 0, 8 * sizeof(float), stream);  // ws is NOT re-poisoned; must zero every call
    k_reduce<<<1024,  256, 0, stream>>>(x, feat, stats);
    k_conv  <<<512,   256, 0, stream>>>(feat, cw, g1, b1, convout, stats);
    k_apply <<<65536, 256, 0, stream>>>(x, convout, g2, b2, stats, out);
}